// Round 19
// baseline (7299.236 us; speedup 1.0000x reference)
//
#include <hip/hip_runtime.h>
#include <cstdint>

typedef unsigned int   u32;
typedef unsigned long long u64;

#define N_PTS 16384
#define S_OUT 4096
#define K_NB  32
#define CAP   1024
#define NWORK 255            // worker blocks (grid = 256 incl. fps block 0)
#define FSTR  32             // flag stride (ints) = 128 B -> one flag per full line

// d_out (f32) element offsets: [4096*256 out][4096*3 centers][4096 batch]
#define OUT_CEN   1048576
#define OUT_BATCH 1060864

__device__ u32 g_perm[N_PTS];
__device__ int g_flag[S_OUT * FSTR];   // 0 = not ready; else selfI+1 (payload IS the atomic)

__device__ __forceinline__ u32 spread3(u32 x) {
    x &= 0x3ffu;
    x = (x | (x << 16)) & 0x030000FFu;
    x = (x | (x << 8))  & 0x0300F00Fu;
    x = (x | (x << 4))  & 0x030C30C3u;
    x = (x | (x << 2))  & 0x09249249u;
    return x;
}

// ---------------- Morton sort + flag re-zero (runs before mega_kernel) ----------------
__global__ __launch_bounds__(1024) void sort_kernel(const float* __restrict__ pos) {
    const int t = threadIdx.x;
    __shared__ u32 sortbuf[N_PTS];                 // 64 KB
    for (int e = t; e < S_OUT * FSTR; e += 1024) g_flag[e] = 0;   // replay-safe reset
    for (int i = 0; i < 16; ++i) {
        int p = t * 16 + i;
        float X = pos[3 * p], Y = pos[3 * p + 1], Z = pos[3 * p + 2];
        int qx = (int)((X + 8.f) * 4.f); qx = qx < 0 ? 0 : (qx > 63 ? 63 : qx);
        int qy = (int)((Y + 8.f) * 4.f); qy = qy < 0 ? 0 : (qy > 63 ? 63 : qy);
        int qz = (int)((Z + 8.f) * 4.f); qz = qz < 0 ? 0 : (qz > 63 ? 63 : qz);
        u32 code = (spread3((u32)qx) << 2) | (spread3((u32)qy) << 1) | spread3((u32)qz);
        sortbuf[p] = (code << 14) | (u32)p;
    }
    __syncthreads();
    for (int k = 2; k <= N_PTS; k <<= 1) {
        for (int j = k >> 1; j >= 1; j >>= 1) {
            for (int e = t; e < (N_PTS >> 1); e += 1024) {
                int i  = ((e & ~(j - 1)) << 1) | (e & (j - 1));
                int p2 = i + j;
                u32 a = sortbuf[i], b = sortbuf[p2];
                bool up = ((i & k) == 0);
                if ((a > b) == up) { sortbuf[i] = b; sortbuf[p2] = a; }
            }
            __syncthreads();
        }
    }
    for (int p = t; p < N_PTS; p += 1024) g_perm[p] = sortbuf[p] & 16383u;
}

// ---------------- mega-kernel: block 0 = fps producer; blocks 1..255 = workers ----------------
// Round 19 = round-17 VERBATIM except the fps branch drops the 16 o##i index
// registers: WRITE 420.9 MB / 4095 iters == 1024 thr x ~26 floats == fps-branch
// scratch spill under the unified 64-VGPR budget (worker branch shares it;
// standalone fps at VGPR 60 never spilled). oi is a pure function of immutable
// g_perm -> the RARE rescan path (1-2 tie-winning threads/iter) reloads it from
// L2 instead. Frees 16 VGPRs ~= the diagnosed spill mass. Math bitwise
// identical (absmax 0.0). Pre-committed read: WRITE collapses -> drag gone;
// WRITE unchanged -> declare roofline at ~6.3 ms.
#define R16(M) M(0) M(1) M(2) M(3) M(4) M(5) M(6) M(7) M(8) M(9) M(10) M(11) M(12) M(13) M(14) M(15)

#define SM_H2  0
#define SM_INP 4224
#define SM_H1  6400
#define SM_H3  4224
#define SM_TOT 12544

__global__ __launch_bounds__(1024) void mega_kernel(const float* __restrict__ pos,
                                                    const float* __restrict__ x,
                                                    const float* __restrict__ W1,
                                                    const float* __restrict__ b1,
                                                    const float* __restrict__ W2,
                                                    const float* __restrict__ b2,
                                                    const float* __restrict__ W3,
                                                    const float* __restrict__ b3,
                                                    float* __restrict__ outF) {
    const int t = threadIdx.x;
    const int lane = t & 63, wid = t >> 6;         // 16 waves

    // fps shared
    __shared__ float warpV[16];
    __shared__ float maxvS;
    __shared__ int   winS;
    // worker shared
    __shared__ float cd2[CAP];
    __shared__ int   cid[CAP];
    __shared__ int   wsum16[16];
    __shared__ int   colsS[32];
    __shared__ int   selfS;
    __shared__ __align__(16) float smem[SM_TOT];

    if (blockIdx.x == 0) {
        // ================= FPS (round-9 structure; o##i reloaded on rescan) =================
        const int base = t * 16;
#define DECLP(i) float px##i, py##i, pz##i, d##i;
        R16(DECLP)
#undef DECLP
        {
#define LOADP(i) { u32 oi = g_perm[base + i] & (u32)(N_PTS - 1); \
                   px##i = pos[3 * oi]; py##i = pos[3 * oi + 1]; pz##i = pos[3 * oi + 2]; }
            R16(LOADP)
#undef LOADP
        }
        float blox = px0, bhix = px0, bloy = py0, bhiy = py0, bloz = pz0, bhiz = pz0;
#define BBOX(i) blox = fminf(blox, px##i); bhix = fmaxf(bhix, px##i); \
                bloy = fminf(bloy, py##i); bhiy = fmaxf(bhiy, py##i); \
                bloz = fminf(bloz, pz##i); bhiz = fmaxf(bhiz, pz##i);
        R16(BBOX)
#undef BBOX
        float qx0 = pos[0], qy0 = pos[1], qz0 = pos[2];
        float lmax = -1.f;
#define INITD(i) { float dx = __fsub_rn(px##i, qx0), dy = __fsub_rn(py##i, qy0), dz = __fsub_rn(pz##i, qz0); \
                   d##i = __fadd_rn(__fadd_rn(__fmul_rn(dx, dx), __fmul_rn(dy, dy)), __fmul_rn(dz, dz)); \
                   lmax = fmaxf(lmax, d##i); }
        R16(INITD)
#undef INITD
        if (t == 0) __hip_atomic_store(&g_flag[0], 1, __ATOMIC_RELAXED, __HIP_MEMORY_SCOPE_AGENT);

        for (int it = 1; it < S_OUT; ++it) {
            float v = lmax;
#pragma unroll
            for (int off = 32; off >= 1; off >>= 1) v = fmaxf(v, __shfl_down(v, off));
            if (lane == 0) warpV[wid] = v;
            __syncthreads();                       // b1
            if (wid == 0) {
                float v2 = (lane < 16) ? warpV[lane] : -1.f;
#pragma unroll
                for (int off = 8; off >= 1; off >>= 1) v2 = fmaxf(v2, __shfl_down(v2, off));
                if (lane == 0) { maxvS = v2; winS = 0x7fffffff; }
            }
            __syncthreads();                       // b2
            float maxv = maxvS;
            if (lmax == maxv) {                    // RARE path: reload orig ids from L2
                int cand = 0x7fffffff;
#define SCAN(i) { int oi = (int)(g_perm[base + i] & (u32)(N_PTS - 1)); \
                  cand = (d##i == maxv && oi < cand) ? oi : cand; }
                R16(SCAN)
#undef SCAN
                atomicMin(&winS, cand);
            }
            __syncthreads();                       // b3
            int wsel = winS & (N_PTS - 1);
            if (t == 0) __hip_atomic_store(&g_flag[it * FSTR], wsel + 1,
                                           __ATOMIC_RELAXED, __HIP_MEMORY_SCOPE_AGENT);
            float wx = pos[3 * wsel], wy = pos[3 * wsel + 1], wz = pos[3 * wsel + 2];
            float dxl = fmaxf(fmaxf(__fsub_rn(blox, wx), __fsub_rn(wx, bhix)), 0.f);
            float dyl = fmaxf(fmaxf(__fsub_rn(bloy, wy), __fsub_rn(wy, bhiy)), 0.f);
            float dzl = fmaxf(fmaxf(__fsub_rn(bloz, wz), __fsub_rn(wz, bhiz)), 0.f);
            float lb = __fadd_rn(__fadd_rn(__fmul_rn(dxl, dxl), __fmul_rn(dyl, dyl)), __fmul_rn(dzl, dzl));
            if (__fmul_rn(lb, 0.99999f) < lmax) {
                float nl = -1.f;
#define UPD(i) { float dx = __fsub_rn(px##i, wx), dy = __fsub_rn(py##i, wy), dz = __fsub_rn(pz##i, wz); \
                 float nd = __fadd_rn(__fadd_rn(__fmul_rn(dx, dx), __fmul_rn(dy, dy)), __fmul_rn(dz, dz)); \
                 d##i = fminf(d##i, nd); nl = fmaxf(nl, d##i); }
                R16(UPD)
#undef UPD
                lmax = nl;
            }
        }
        return;
    }

    // ================= WORKERS: centers s = (b-1) + NWORK*j =================
    for (int s = (int)blockIdx.x - 1; s < S_OUT; s += NWORK) {
        if (t == 0) {
            int v;
            while ((v = __hip_atomic_load(&g_flag[s * FSTR], __ATOMIC_RELAXED,
                                          __HIP_MEMORY_SCOPE_AGENT)) == 0)
                __builtin_amdgcn_s_sleep(127);     // relaxed coherent load poll
            selfS = v - 1;
        }
        __syncthreads();                           // B0 (also orders prev pool reads vs staging)
        const int selfI = selfS & (N_PTS - 1);
        if (t < 3) outF[OUT_CEN + 3 * s + t] = pos[3 * selfI + t];
        if (t == 3) outF[OUT_BATCH + s] = 0.0f;
        const float cx = pos[3 * selfI], cy = pos[3 * selfI + 1], cz = pos[3 * selfI + 2];
        const float cs = __fadd_rn(__fadd_rn(__fmul_rn(cx, cx), __fmul_rn(cy, cy)), __fmul_rn(cz, cz));

        // ---- radius pass 1: 16 pts/thread, stripes in index order ----
        const int p0 = t * 16;
        int c = 0;
        for (int i = 0; i < 16; ++i) {
            int p = p0 + i;
            float X = pos[3 * p], Y = pos[3 * p + 1], Z = pos[3 * p + 2];
            float ps = __fadd_rn(__fadd_rn(__fmul_rn(X, X), __fmul_rn(Y, Y)), __fmul_rn(Z, Z));
            float dt = __fmaf_rn(cz, Z, __fmaf_rn(cy, Y, __fmul_rn(cx, X)));
            float d2 = __fsub_rn(__fadd_rn(cs, ps), __fmul_rn(2.0f, dt));
            c += (d2 <= 0.04f) ? 1 : 0;
        }
        int inc = c;
#pragma unroll
        for (int off = 1; off < 64; off <<= 1) {
            int o = __shfl_up(inc, off);
            if (lane >= off) inc += o;
        }
        if (lane == 63) wsum16[wid] = inc;
        __syncthreads();                           // B1
        int pre = 0, total = 0;
#pragma unroll
        for (int w2 = 0; w2 < 16; ++w2) {
            int wv2 = wsum16[w2];
            pre += (w2 < wid) ? wv2 : 0;
            total += wv2;
        }
        int w = pre + (inc - c);                   // exclusive base, index-ordered
        for (int i = 0; i < 16; ++i) {
            int p = p0 + i;
            float X = pos[3 * p], Y = pos[3 * p + 1], Z = pos[3 * p + 2];
            float ps = __fadd_rn(__fadd_rn(__fmul_rn(X, X), __fmul_rn(Y, Y)), __fmul_rn(Z, Z));
            float dt = __fmaf_rn(cz, Z, __fmaf_rn(cy, Y, __fmul_rn(cx, X)));
            float d2 = __fsub_rn(__fadd_rn(cs, ps), __fmul_rn(2.0f, dt));
            if (d2 <= 0.04f) {
                if (w < CAP) { cd2[w] = d2; cid[w] = p; }
                ++w;
            }
        }
        __syncthreads();                           // B2
        const int n = min(total, CAP);
        if (n <= K_NB) {
            if (t < K_NB) colsS[t] = (t < n) ? cid[t] : selfI;
        } else if (wid == 0) {
            // wave 0: K smallest by (d2, slot), scanning LDS each round.
            for (int k = 0; k < K_NB; ++k) {
                u64 best = ~0ull;
                for (int q = lane; q < n; q += 64) {
                    u32 fb = __float_as_uint(cd2[q]);
                    fb = (fb >> 31) ? ~fb : (fb | 0x80000000u);   // total order
                    u64 key = ((u64)fb << 32) | (u32)q;
                    best = best < key ? best : key;
                }
#pragma unroll
                for (int m = 1; m < 64; m <<= 1) {
                    u64 o = __shfl_xor(best, m);
                    best = (o < best) ? o : best;
                }
                int q = (int)(u32)(best & 0xffffffffu) & (CAP - 1);
                if (lane == 0) colsS[k] = cid[q];
                cd2[q] = __uint_as_float(0x7f7fffffu);   // all lanes, same addr+value
            }
        }
        __syncthreads();                           // B3
        const int nn = (n < K_NB) ? n : K_NB;      // valid rows for pool

        // ---- MLP staging: inp = [x_j (64) | pos_j - center (3) | 0] ----
        float* inp = smem + SM_INP;
        float* h1s = smem + SM_H1;
        float* h2s = smem + SM_H2;
        float* h3  = smem + SM_H3;
        if (t < 512) {                             // one float4 each: 32 rows x 16
            const int r = t >> 4, sg = t & 15;
            const float4* x4 = (const float4*)x;
            *(float4*)&inp[r * 68 + sg * 4] = x4[(colsS[r] & (N_PTS - 1)) * 16 + sg];
        } else if (t < 544) {
            const int r = t - 512;
            int j = colsS[r] & (N_PTS - 1);
            inp[r * 68 + 64] = __fsub_rn(pos[3 * j],     cx);
            inp[r * 68 + 65] = __fsub_rn(pos[3 * j + 1], cy);
            inp[r * 68 + 66] = __fsub_rn(pos[3 * j + 2], cz);
            inp[r * 68 + 67] = 0.f;
        }
        __syncthreads();                           // B4
        // ---- layer 1: 1024 threads, 4 cols each; k-ascending order per output ----
        {
            const int r = t >> 5, c0 = (t & 31) * 4;
            float a0 = 0.f, a1 = 0.f, a2 = 0.f, a3 = 0.f;
            for (int k = 0; k < 64; ++k) {
                float a = inp[r * 68 + k];
                float4 ww = *(const float4*)&W1[k * 128 + c0];
                a0 += a * ww.x; a1 += a * ww.y; a2 += a * ww.z; a3 += a * ww.w;
            }
#pragma unroll
            for (int q = 0; q < 3; ++q) {
                float a = inp[r * 68 + 64 + q];
                float4 ww = *(const float4*)&W1[(64 + q) * 128 + c0];
                a0 += a * ww.x; a1 += a * ww.y; a2 += a * ww.z; a3 += a * ww.w;
            }
            float4 bb = *(const float4*)&b1[c0];
            h1s[r * 132 + c0]     = fmaxf(a0 + bb.x, 0.f);
            h1s[r * 132 + c0 + 1] = fmaxf(a1 + bb.y, 0.f);
            h1s[r * 132 + c0 + 2] = fmaxf(a2 + bb.z, 0.f);
            h1s[r * 132 + c0 + 3] = fmaxf(a3 + bb.w, 0.f);
        }
        __syncthreads();                           // B5
        // ---- layer 2 ----
        {
            const int r = t >> 5, c0 = (t & 31) * 4;
            float a0 = 0.f, a1 = 0.f, a2 = 0.f, a3 = 0.f;
            for (int k = 0; k < 128; ++k) {
                float a = h1s[r * 132 + k];
                float4 ww = *(const float4*)&W2[k * 128 + c0];
                a0 += a * ww.x; a1 += a * ww.y; a2 += a * ww.z; a3 += a * ww.w;
            }
            float4 bb = *(const float4*)&b2[c0];
            h2s[r * 132 + c0]     = fmaxf(a0 + bb.x, 0.f);
            h2s[r * 132 + c0 + 1] = fmaxf(a1 + bb.y, 0.f);
            h2s[r * 132 + c0 + 2] = fmaxf(a2 + bb.z, 0.f);
            h2s[r * 132 + c0 + 3] = fmaxf(a3 + bb.w, 0.f);
        }
        __syncthreads();                           // B6
        // ---- layer 3: 8 cols each -> h3 (aliases inp/h1s; both dead) ----
        {
            const int r = t >> 5, c0 = (t & 31) * 8;
            float a0 = 0.f, a1 = 0.f, a2 = 0.f, a3 = 0.f, a4 = 0.f, a5 = 0.f, a6 = 0.f, a7 = 0.f;
            for (int k = 0; k < 128; ++k) {
                float a = h2s[r * 132 + k];
                float4 w0 = *(const float4*)&W3[k * 256 + c0];
                float4 w1 = *(const float4*)&W3[k * 256 + c0 + 4];
                a0 += a * w0.x; a1 += a * w0.y; a2 += a * w0.z; a3 += a * w0.w;
                a4 += a * w1.x; a5 += a * w1.y; a6 += a * w1.z; a7 += a * w1.w;
            }
            __syncthreads();                       // B7: all inp/h1s reads done before alias write
            float4 b0 = *(const float4*)&b3[c0];
            float4 b1v = *(const float4*)&b3[c0 + 4];
            h3[r * 260 + c0]     = a0 + b0.x;  h3[r * 260 + c0 + 1] = a1 + b0.y;
            h3[r * 260 + c0 + 2] = a2 + b0.z;  h3[r * 260 + c0 + 3] = a3 + b0.w;
            h3[r * 260 + c0 + 4] = a4 + b1v.x; h3[r * 260 + c0 + 5] = a5 + b1v.y;
            h3[r * 260 + c0 + 6] = a6 + b1v.z; h3[r * 260 + c0 + 7] = a7 + b1v.w;
        }
        __syncthreads();                           // B8
        // ---- masked max pool over valid rows 0..nn-1 ----
        if (t < 256) {
            float m = h3[t];                       // nn >= 1 (self in own ball)
            for (int rr = 1; rr < nn; ++rr) m = fmaxf(m, h3[rr * 260 + t]);
            outF[s * 256 + t] = m;
        }
        __syncthreads();                           // B9: pool done before next center reuses smem
    }
}

extern "C" void kernel_launch(void* const* d_in, const int* in_sizes, int n_in,
                              void* d_out, int out_size, void* d_ws, size_t ws_size,
                              hipStream_t stream) {
    const float* x   = (const float*)d_in[0];
    const float* pos = (const float*)d_in[1];
    const float* W1 = (const float*)d_in[3]; const float* b1 = (const float*)d_in[4];
    const float* W2 = (const float*)d_in[5]; const float* b2 = (const float*)d_in[6];
    const float* W3 = (const float*)d_in[7]; const float* b3 = (const float*)d_in[8];
    float* outF = (float*)d_out;
    (void)d_ws; (void)ws_size; (void)in_sizes; (void)n_in; (void)out_size;

    hipLaunchKernelGGL(sort_kernel, dim3(1), dim3(1024), 0, stream, pos);
    hipLaunchKernelGGL(mega_kernel, dim3(NWORK + 1), dim3(1024), 0, stream,
                       pos, x, W1, b1, W2, b2, W3, b3, outF);
}

// Round 20
// 6256.356 us; speedup vs baseline: 1.1667x; 1.1667x over previous
//
#include <hip/hip_runtime.h>
#include <cstdint>

typedef unsigned int   u32;
typedef unsigned long long u64;

#define N_PTS 16384
#define S_OUT 4096
#define K_NB  32
#define CAP   1024
#define NWORK 255            // worker blocks (grid = 256 incl. fps block 0)
#define FSTR  32             // flag stride (ints) = 128 B -> one flag per full line

// d_out (f32) element offsets: [4096*256 out][4096*3 centers][4096 batch]
#define OUT_CEN   1048576
#define OUT_BATCH 1060864

__device__ u32 g_perm[N_PTS];
__device__ int g_flag[S_OUT * FSTR];   // 0 = not ready; else selfI+1 (payload IS the atomic)

__device__ __forceinline__ u32 spread3(u32 x) {
    x &= 0x3ffu;
    x = (x | (x << 16)) & 0x030000FFu;
    x = (x | (x << 8))  & 0x0300F00Fu;
    x = (x | (x << 4))  & 0x030C30C3u;
    x = (x | (x << 2))  & 0x09249249u;
    return x;
}

// ---------------- Morton sort + flag re-zero (runs before mega_kernel) ----------------
__global__ __launch_bounds__(1024) void sort_kernel(const float* __restrict__ pos) {
    const int t = threadIdx.x;
    __shared__ u32 sortbuf[N_PTS];                 // 64 KB
    for (int e = t; e < S_OUT * FSTR; e += 1024) g_flag[e] = 0;   // replay-safe reset
    for (int i = 0; i < 16; ++i) {
        int p = t * 16 + i;
        float X = pos[3 * p], Y = pos[3 * p + 1], Z = pos[3 * p + 2];
        int qx = (int)((X + 8.f) * 4.f); qx = qx < 0 ? 0 : (qx > 63 ? 63 : qx);
        int qy = (int)((Y + 8.f) * 4.f); qy = qy < 0 ? 0 : (qy > 63 ? 63 : qy);
        int qz = (int)((Z + 8.f) * 4.f); qz = qz < 0 ? 0 : (qz > 63 ? 63 : qz);
        u32 code = (spread3((u32)qx) << 2) | (spread3((u32)qy) << 1) | spread3((u32)qz);
        sortbuf[p] = (code << 14) | (u32)p;
    }
    __syncthreads();
    for (int k = 2; k <= N_PTS; k <<= 1) {
        for (int j = k >> 1; j >= 1; j >>= 1) {
            for (int e = t; e < (N_PTS >> 1); e += 1024) {
                int i  = ((e & ~(j - 1)) << 1) | (e & (j - 1));
                int p2 = i + j;
                u32 a = sortbuf[i], b = sortbuf[p2];
                bool up = ((i & k) == 0);
                if ((a > b) == up) { sortbuf[i] = b; sortbuf[p2] = a; }
            }
            __syncthreads();
        }
    }
    for (int p = t; p < N_PTS; p += 1024) g_perm[p] = sortbuf[p] & 16383u;
}

// ---------------- mega-kernel: block 0 = fps producer; blocks 1..255 = workers ----------------
// Round 20 = round-17 VERBATIM (measured optimum: 6292us total, absmax 0.0).
// Ledger: fps reduce alternatives (r5/8/10/11) all regressed vs the r9 3-barrier
// tree; Morton+bbox prune kept (-27%); producer-consumer fusion kept (-7%);
// co-residency knobs (r13-19: acquire->relaxed, launch_bounds, waves_per_eu,
// NWORK, batched publish, o##i removal) ALL null or regressions — the 421 MB
// WRITE / 3.0 GB FETCH is deterministic worker-side traffic, and the ~700us
// fps drag is intrinsic L2/L3 co-residency interference. Serial FPS chain
// (4095 dependent argmax steps, ~1.4us each, 1 CU) is latency-bound:
// VALUBusy 2.8%, HBM 7%. Practical floor for this decomposition.
#define R16(M) M(0) M(1) M(2) M(3) M(4) M(5) M(6) M(7) M(8) M(9) M(10) M(11) M(12) M(13) M(14) M(15)

#define SM_H2  0
#define SM_INP 4224
#define SM_H1  6400
#define SM_H3  4224
#define SM_TOT 12544

__global__ __launch_bounds__(1024) void mega_kernel(const float* __restrict__ pos,
                                                    const float* __restrict__ x,
                                                    const float* __restrict__ W1,
                                                    const float* __restrict__ b1,
                                                    const float* __restrict__ W2,
                                                    const float* __restrict__ b2,
                                                    const float* __restrict__ W3,
                                                    const float* __restrict__ b3,
                                                    float* __restrict__ outF) {
    const int t = threadIdx.x;
    const int lane = t & 63, wid = t >> 6;         // 16 waves

    // fps shared
    __shared__ float warpV[16];
    __shared__ float maxvS;
    __shared__ int   winS;
    // worker shared
    __shared__ float cd2[CAP];
    __shared__ int   cid[CAP];
    __shared__ int   wsum16[16];
    __shared__ int   colsS[32];
    __shared__ int   selfS;
    __shared__ __align__(16) float smem[SM_TOT];

    if (blockIdx.x == 0) {
        // ================= FPS (round-9 verbatim + flag publish) =================
#define DECLP(i) float px##i, py##i, pz##i, d##i; u32 o##i;
        R16(DECLP)
#undef DECLP
        {
            const int base = t * 16;
#define LOADP(i) { u32 oi = g_perm[base + i] & (u32)(N_PTS - 1); o##i = oi; \
                   px##i = pos[3 * oi]; py##i = pos[3 * oi + 1]; pz##i = pos[3 * oi + 2]; }
            R16(LOADP)
#undef LOADP
        }
        float blox = px0, bhix = px0, bloy = py0, bhiy = py0, bloz = pz0, bhiz = pz0;
#define BBOX(i) blox = fminf(blox, px##i); bhix = fmaxf(bhix, px##i); \
                bloy = fminf(bloy, py##i); bhiy = fmaxf(bhiy, py##i); \
                bloz = fminf(bloz, pz##i); bhiz = fmaxf(bhiz, pz##i);
        R16(BBOX)
#undef BBOX
        float qx0 = pos[0], qy0 = pos[1], qz0 = pos[2];
        float lmax = -1.f;
#define INITD(i) { float dx = __fsub_rn(px##i, qx0), dy = __fsub_rn(py##i, qy0), dz = __fsub_rn(pz##i, qz0); \
                   d##i = __fadd_rn(__fadd_rn(__fmul_rn(dx, dx), __fmul_rn(dy, dy)), __fmul_rn(dz, dz)); \
                   lmax = fmaxf(lmax, d##i); }
        R16(INITD)
#undef INITD
        if (t == 0) __hip_atomic_store(&g_flag[0], 1, __ATOMIC_RELAXED, __HIP_MEMORY_SCOPE_AGENT);

        for (int it = 1; it < S_OUT; ++it) {
            float v = lmax;
#pragma unroll
            for (int off = 32; off >= 1; off >>= 1) v = fmaxf(v, __shfl_down(v, off));
            if (lane == 0) warpV[wid] = v;
            __syncthreads();                       // b1
            if (wid == 0) {
                float v2 = (lane < 16) ? warpV[lane] : -1.f;
#pragma unroll
                for (int off = 8; off >= 1; off >>= 1) v2 = fmaxf(v2, __shfl_down(v2, off));
                if (lane == 0) { maxvS = v2; winS = 0x7fffffff; }
            }
            __syncthreads();                       // b2
            float maxv = maxvS;
            if (lmax == maxv) {
                int cand = 0x7fffffff;
#define SCAN(i) cand = (d##i == maxv && (int)o##i < cand) ? (int)o##i : cand;
                R16(SCAN)
#undef SCAN
                atomicMin(&winS, cand);
            }
            __syncthreads();                       // b3
            int wsel = winS & (N_PTS - 1);
            if (t == 0) __hip_atomic_store(&g_flag[it * FSTR], wsel + 1,
                                           __ATOMIC_RELAXED, __HIP_MEMORY_SCOPE_AGENT);
            float wx = pos[3 * wsel], wy = pos[3 * wsel + 1], wz = pos[3 * wsel + 2];
            float dxl = fmaxf(fmaxf(__fsub_rn(blox, wx), __fsub_rn(wx, bhix)), 0.f);
            float dyl = fmaxf(fmaxf(__fsub_rn(bloy, wy), __fsub_rn(wy, bhiy)), 0.f);
            float dzl = fmaxf(fmaxf(__fsub_rn(bloz, wz), __fsub_rn(wz, bhiz)), 0.f);
            float lb = __fadd_rn(__fadd_rn(__fmul_rn(dxl, dxl), __fmul_rn(dyl, dyl)), __fmul_rn(dzl, dzl));
            if (__fmul_rn(lb, 0.99999f) < lmax) {
                float nl = -1.f;
#define UPD(i) { float dx = __fsub_rn(px##i, wx), dy = __fsub_rn(py##i, wy), dz = __fsub_rn(pz##i, wz); \
                 float nd = __fadd_rn(__fadd_rn(__fmul_rn(dx, dx), __fmul_rn(dy, dy)), __fmul_rn(dz, dz)); \
                 d##i = fminf(d##i, nd); nl = fmaxf(nl, d##i); }
                R16(UPD)
#undef UPD
                lmax = nl;
            }
        }
        return;
    }

    // ================= WORKERS: centers s = (b-1) + NWORK*j =================
    for (int s = (int)blockIdx.x - 1; s < S_OUT; s += NWORK) {
        if (t == 0) {
            int v;
            while ((v = __hip_atomic_load(&g_flag[s * FSTR], __ATOMIC_RELAXED,
                                          __HIP_MEMORY_SCOPE_AGENT)) == 0)
                __builtin_amdgcn_s_sleep(127);     // relaxed coherent load poll
            selfS = v - 1;
        }
        __syncthreads();                           // B0 (also orders prev pool reads vs staging)
        const int selfI = selfS & (N_PTS - 1);
        if (t < 3) outF[OUT_CEN + 3 * s + t] = pos[3 * selfI + t];
        if (t == 3) outF[OUT_BATCH + s] = 0.0f;
        const float cx = pos[3 * selfI], cy = pos[3 * selfI + 1], cz = pos[3 * selfI + 2];
        const float cs = __fadd_rn(__fadd_rn(__fmul_rn(cx, cx), __fmul_rn(cy, cy)), __fmul_rn(cz, cz));

        // ---- radius pass 1: 16 pts/thread, stripes in index order ----
        const int p0 = t * 16;
        int c = 0;
        for (int i = 0; i < 16; ++i) {
            int p = p0 + i;
            float X = pos[3 * p], Y = pos[3 * p + 1], Z = pos[3 * p + 2];
            float ps = __fadd_rn(__fadd_rn(__fmul_rn(X, X), __fmul_rn(Y, Y)), __fmul_rn(Z, Z));
            float dt = __fmaf_rn(cz, Z, __fmaf_rn(cy, Y, __fmul_rn(cx, X)));
            float d2 = __fsub_rn(__fadd_rn(cs, ps), __fmul_rn(2.0f, dt));
            c += (d2 <= 0.04f) ? 1 : 0;
        }
        int inc = c;
#pragma unroll
        for (int off = 1; off < 64; off <<= 1) {
            int o = __shfl_up(inc, off);
            if (lane >= off) inc += o;
        }
        if (lane == 63) wsum16[wid] = inc;
        __syncthreads();                           // B1
        int pre = 0, total = 0;
#pragma unroll
        for (int w2 = 0; w2 < 16; ++w2) {
            int wv2 = wsum16[w2];
            pre += (w2 < wid) ? wv2 : 0;
            total += wv2;
        }
        int w = pre + (inc - c);                   // exclusive base, index-ordered
        for (int i = 0; i < 16; ++i) {
            int p = p0 + i;
            float X = pos[3 * p], Y = pos[3 * p + 1], Z = pos[3 * p + 2];
            float ps = __fadd_rn(__fadd_rn(__fmul_rn(X, X), __fmul_rn(Y, Y)), __fmul_rn(Z, Z));
            float dt = __fmaf_rn(cz, Z, __fmaf_rn(cy, Y, __fmul_rn(cx, X)));
            float d2 = __fsub_rn(__fadd_rn(cs, ps), __fmul_rn(2.0f, dt));
            if (d2 <= 0.04f) {
                if (w < CAP) { cd2[w] = d2; cid[w] = p; }
                ++w;
            }
        }
        __syncthreads();                           // B2
        const int n = min(total, CAP);
        if (n <= K_NB) {
            if (t < K_NB) colsS[t] = (t < n) ? cid[t] : selfI;
        } else if (wid == 0) {
            // wave 0: K smallest by (d2, slot), scanning LDS each round.
            // Slots are orig-index-ordered => (d2, slot) lexicographic == stable
            // top_k set. ~4 live regs; nothing to spill.
            for (int k = 0; k < K_NB; ++k) {
                u64 best = ~0ull;
                for (int q = lane; q < n; q += 64) {
                    u32 fb = __float_as_uint(cd2[q]);
                    fb = (fb >> 31) ? ~fb : (fb | 0x80000000u);   // total order
                    u64 key = ((u64)fb << 32) | (u32)q;
                    best = best < key ? best : key;
                }
#pragma unroll
                for (int m = 1; m < 64; m <<= 1) {
                    u64 o = __shfl_xor(best, m);
                    best = (o < best) ? o : best;
                }
                int q = (int)(u32)(best & 0xffffffffu) & (CAP - 1);
                if (lane == 0) colsS[k] = cid[q];
                cd2[q] = __uint_as_float(0x7f7fffffu);   // all lanes, same addr+value
            }
        }
        __syncthreads();                           // B3
        const int nn = (n < K_NB) ? n : K_NB;      // valid rows for pool

        // ---- MLP staging: inp = [x_j (64) | pos_j - center (3) | 0] ----
        float* inp = smem + SM_INP;
        float* h1s = smem + SM_H1;
        float* h2s = smem + SM_H2;
        float* h3  = smem + SM_H3;
        if (t < 512) {                             // one float4 each: 32 rows x 16
            const int r = t >> 4, sg = t & 15;
            const float4* x4 = (const float4*)x;
            *(float4*)&inp[r * 68 + sg * 4] = x4[(colsS[r] & (N_PTS - 1)) * 16 + sg];
        } else if (t < 544) {
            const int r = t - 512;
            int j = colsS[r] & (N_PTS - 1);
            inp[r * 68 + 64] = __fsub_rn(pos[3 * j],     cx);
            inp[r * 68 + 65] = __fsub_rn(pos[3 * j + 1], cy);
            inp[r * 68 + 66] = __fsub_rn(pos[3 * j + 2], cz);
            inp[r * 68 + 67] = 0.f;
        }
        __syncthreads();                           // B4
        // ---- layer 1: 1024 threads, 4 cols each; k-ascending order per output ----
        {
            const int r = t >> 5, c0 = (t & 31) * 4;
            float a0 = 0.f, a1 = 0.f, a2 = 0.f, a3 = 0.f;
            for (int k = 0; k < 64; ++k) {
                float a = inp[r * 68 + k];
                float4 ww = *(const float4*)&W1[k * 128 + c0];
                a0 += a * ww.x; a1 += a * ww.y; a2 += a * ww.z; a3 += a * ww.w;
            }
#pragma unroll
            for (int q = 0; q < 3; ++q) {
                float a = inp[r * 68 + 64 + q];
                float4 ww = *(const float4*)&W1[(64 + q) * 128 + c0];
                a0 += a * ww.x; a1 += a * ww.y; a2 += a * ww.z; a3 += a * ww.w;
            }
            float4 bb = *(const float4*)&b1[c0];
            h1s[r * 132 + c0]     = fmaxf(a0 + bb.x, 0.f);
            h1s[r * 132 + c0 + 1] = fmaxf(a1 + bb.y, 0.f);
            h1s[r * 132 + c0 + 2] = fmaxf(a2 + bb.z, 0.f);
            h1s[r * 132 + c0 + 3] = fmaxf(a3 + bb.w, 0.f);
        }
        __syncthreads();                           // B5
        // ---- layer 2 ----
        {
            const int r = t >> 5, c0 = (t & 31) * 4;
            float a0 = 0.f, a1 = 0.f, a2 = 0.f, a3 = 0.f;
            for (int k = 0; k < 128; ++k) {
                float a = h1s[r * 132 + k];
                float4 ww = *(const float4*)&W2[k * 128 + c0];
                a0 += a * ww.x; a1 += a * ww.y; a2 += a * ww.z; a3 += a * ww.w;
            }
            float4 bb = *(const float4*)&b2[c0];
            h2s[r * 132 + c0]     = fmaxf(a0 + bb.x, 0.f);
            h2s[r * 132 + c0 + 1] = fmaxf(a1 + bb.y, 0.f);
            h2s[r * 132 + c0 + 2] = fmaxf(a2 + bb.z, 0.f);
            h2s[r * 132 + c0 + 3] = fmaxf(a3 + bb.w, 0.f);
        }
        __syncthreads();                           // B6
        // ---- layer 3: 8 cols each -> h3 (aliases inp/h1s; both dead) ----
        {
            const int r = t >> 5, c0 = (t & 31) * 8;
            float a0 = 0.f, a1 = 0.f, a2 = 0.f, a3 = 0.f, a4 = 0.f, a5 = 0.f, a6 = 0.f, a7 = 0.f;
            for (int k = 0; k < 128; ++k) {
                float a = h2s[r * 132 + k];
                float4 w0 = *(const float4*)&W3[k * 256 + c0];
                float4 w1 = *(const float4*)&W3[k * 256 + c0 + 4];
                a0 += a * w0.x; a1 += a * w0.y; a2 += a * w0.z; a3 += a * w0.w;
                a4 += a * w1.x; a5 += a * w1.y; a6 += a * w1.z; a7 += a * w1.w;
            }
            __syncthreads();                       // B7: all inp/h1s reads done before alias write
            float4 b0 = *(const float4*)&b3[c0];
            float4 b1v = *(const float4*)&b3[c0 + 4];
            h3[r * 260 + c0]     = a0 + b0.x;  h3[r * 260 + c0 + 1] = a1 + b0.y;
            h3[r * 260 + c0 + 2] = a2 + b0.z;  h3[r * 260 + c0 + 3] = a3 + b0.w;
            h3[r * 260 + c0 + 4] = a4 + b1v.x; h3[r * 260 + c0 + 5] = a5 + b1v.y;
            h3[r * 260 + c0 + 6] = a6 + b1v.z; h3[r * 260 + c0 + 7] = a7 + b1v.w;
        }
        __syncthreads();                           // B8
        // ---- masked max pool over valid rows 0..nn-1 ----
        if (t < 256) {
            float m = h3[t];                       // nn >= 1 (self in own ball)
            for (int rr = 1; rr < nn; ++rr) m = fmaxf(m, h3[rr * 260 + t]);
            outF[s * 256 + t] = m;
        }
        __syncthreads();                           // B9: pool done before next center reuses smem
    }
}

extern "C" void kernel_launch(void* const* d_in, const int* in_sizes, int n_in,
                              void* d_out, int out_size, void* d_ws, size_t ws_size,
                              hipStream_t stream) {
    const float* x   = (const float*)d_in[0];
    const float* pos = (const float*)d_in[1];
    const float* W1 = (const float*)d_in[3]; const float* b1 = (const float*)d_in[4];
    const float* W2 = (const float*)d_in[5]; const float* b2 = (const float*)d_in[6];
    const float* W3 = (const float*)d_in[7]; const float* b3 = (const float*)d_in[8];
    float* outF = (float*)d_out;
    (void)d_ws; (void)ws_size; (void)in_sizes; (void)n_in; (void)out_size;

    hipLaunchKernelGGL(sort_kernel, dim3(1), dim3(1024), 0, stream, pos);
    hipLaunchKernelGGL(mega_kernel, dim3(NWORK + 1), dim3(1024), 0, stream,
                       pos, x, W1, b1, W2, b2, W3, b3, outF);
}